// Round 1
// baseline (641.840 us; speedup 1.0000x reference)
//
#include <hip/hip_runtime.h>
#include <stdint.h>
#include <math.h>

// Problem dims
#define BS_  256
#define NSEQ 128
#define HH   512
#define DD   1152      // 2H + Z
#define VV   32000
#define BN_  (BS_*NSEQ)  // 32768

typedef float  f32x4  __attribute__((ext_vector_type(4)));
typedef __bf16 bf16x8 __attribute__((ext_vector_type(8)));

__device__ __forceinline__ f32x4 mfma16(bf16x8 a, bf16x8 b, f32x4 c) {
    return __builtin_amdgcn_mfma_f32_16x16x32_bf16(a, b, c, 0, 0, 0);
}

__device__ __forceinline__ bf16x8 pack8(f32x4 a, f32x4 b) {
    bf16x8 v;
    v[0] = (__bf16)a[0]; v[1] = (__bf16)a[1]; v[2] = (__bf16)a[2]; v[3] = (__bf16)a[3];
    v[4] = (__bf16)b[0]; v[5] = (__bf16)b[1]; v[6] = (__bf16)b[2]; v[7] = (__bf16)b[3];
    return v;
}

// ---------------------------------------------------------------------------
// Generic MFMA GEMM: C[M,N] = A[M,K] * B[N,K]^T + bias, all f32 in memory,
// bf16 in-flight. Tile 64x64, 256 threads (4 waves, wave w owns rows w*16..+15).
// grid = (N/64, M/64)
// ---------------------------------------------------------------------------
__global__ __launch_bounds__(256) void k_gemm_bias(
    const float* __restrict__ A, const float* __restrict__ B,
    const float* __restrict__ bias, float* __restrict__ C,
    int K, int ldc)
{
    const int cb = blockIdx.x * 64;
    const int rb = blockIdx.y * 64;
    const int t  = threadIdx.x;
    const int w = t >> 6, lane = t & 63, g = lane >> 4, r = lane & 15;
    const int s_row = t >> 2, s_kc = t & 3;

    __shared__ bf16x8 sm[2][2][256];   // [buf][A/B][kg*64 + row]

    const float* Ap = A + (size_t)(rb + s_row) * K + s_kc * 8;
    const float* Bp = B + (size_t)(cb + s_row) * K + s_kc * 8;

    const int KS = K >> 5;
    f32x4 pa0 = *(const f32x4*)Ap, pa1 = *(const f32x4*)(Ap + 4);
    f32x4 pb0 = *(const f32x4*)Bp, pb1 = *(const f32x4*)(Bp + 4);

    f32x4 acc[4] = {{0,0,0,0},{0,0,0,0},{0,0,0,0},{0,0,0,0}};

    for (int kb = 0; kb < KS; ++kb) {
        sm[kb & 1][0][s_kc * 64 + s_row] = pack8(pa0, pa1);
        sm[kb & 1][1][s_kc * 64 + s_row] = pack8(pb0, pb1);
        __syncthreads();
        if (kb + 1 < KS) {
            const float* a2 = Ap + (kb + 1) * 32;
            const float* b2 = Bp + (kb + 1) * 32;
            pa0 = *(const f32x4*)a2; pa1 = *(const f32x4*)(a2 + 4);
            pb0 = *(const f32x4*)b2; pb1 = *(const f32x4*)(b2 + 4);
        }
        bf16x8 af = sm[kb & 1][0][g * 64 + w * 16 + r];
        #pragma unroll
        for (int j = 0; j < 4; ++j) {
            bf16x8 bf = sm[kb & 1][1][g * 64 + j * 16 + r];
            acc[j] = mfma16(af, bf, acc[j]);
        }
    }
    #pragma unroll
    for (int j = 0; j < 4; ++j) {
        int col = cb + j * 16 + r;
        float bv = bias ? bias[col] : 0.f;
        #pragma unroll
        for (int q = 0; q < 4; ++q) {
            int row = rb + w * 16 + g * 4 + q;
            C[(size_t)row * ldc + col] = acc[j][q] + bv;
        }
    }
}

// ---------------------------------------------------------------------------
// K1: prev_h (256x1152) against virtual concat [W2e(512) | W2s(512) | w_hh(3456)]
// grid = (4480/64, 256/64); writes dt_e, dt_s, gh (gh gets +b_hh)
// ---------------------------------------------------------------------------
__global__ __launch_bounds__(256) void k_prevh(
    const float* __restrict__ prev_h, const float* __restrict__ W2e,
    const float* __restrict__ W2s, const float* __restrict__ w_hh,
    const float* __restrict__ b_hh,
    float* __restrict__ dt_e, float* __restrict__ dt_s, float* __restrict__ gh)
{
    const int cb = blockIdx.x * 64;
    const int rb = blockIdx.y * 64;
    const int t  = threadIdx.x;
    const int w = t >> 6, lane = t & 63, g = lane >> 4, r = lane & 15;
    const int s_row = t >> 2, s_kc = t & 3;
    const int K = DD;

    __shared__ bf16x8 sm[2][2][256];

    const float* Ap = prev_h + (size_t)(rb + s_row) * K + s_kc * 8;
    const float* Bp;
    {
        int brow = cb + s_row;
        if (cb < 512)        Bp = W2e + (size_t)brow * K;
        else if (cb < 1024)  Bp = W2s + (size_t)(brow - 512) * K;
        else                 Bp = w_hh + (size_t)(brow - 1024) * K;
        Bp += s_kc * 8;
    }

    const int KS = K >> 5;   // 36
    f32x4 pa0 = *(const f32x4*)Ap, pa1 = *(const f32x4*)(Ap + 4);
    f32x4 pb0 = *(const f32x4*)Bp, pb1 = *(const f32x4*)(Bp + 4);

    f32x4 acc[4] = {{0,0,0,0},{0,0,0,0},{0,0,0,0},{0,0,0,0}};

    for (int kb = 0; kb < KS; ++kb) {
        sm[kb & 1][0][s_kc * 64 + s_row] = pack8(pa0, pa1);
        sm[kb & 1][1][s_kc * 64 + s_row] = pack8(pb0, pb1);
        __syncthreads();
        if (kb + 1 < KS) {
            const float* a2 = Ap + (kb + 1) * 32;
            const float* b2 = Bp + (kb + 1) * 32;
            pa0 = *(const f32x4*)a2; pa1 = *(const f32x4*)(a2 + 4);
            pb0 = *(const f32x4*)b2; pb1 = *(const f32x4*)(b2 + 4);
        }
        bf16x8 af = sm[kb & 1][0][g * 64 + w * 16 + r];
        #pragma unroll
        for (int j = 0; j < 4; ++j) {
            bf16x8 bf = sm[kb & 1][1][g * 64 + j * 16 + r];
            acc[j] = mfma16(af, bf, acc[j]);
        }
    }

    #pragma unroll
    for (int j = 0; j < 4; ++j) {
        int col = cb + j * 16 + r;
        #pragma unroll
        for (int q = 0; q < 4; ++q) {
            int row = rb + w * 16 + g * 4 + q;
            float v = acc[j][q];
            if (cb < 512)       dt_e[(size_t)row * 512 + col] = v;
            else if (cb < 1024) dt_s[(size_t)row * 512 + (col - 512)] = v;
            else {
                int c0 = col - 1024;
                gh[(size_t)row * 3456 + c0] = v + b_hh[c0];
            }
        }
    }
}

// ---------------------------------------------------------------------------
// K2: attention u[b,n] = sum_k vt[k] * tanh( (enc @ W1^T)[b,n,k] + dt[b,k] )
// Block: 512 threads (8 waves). 64 (b,n)-rows staged fully in LDS (bf16,
// fragment-major, XOR-swizzled). W1 streamed col-chunk 256 x k-step 64,
// double buffered. Fused tanh/vt epilogue + column reduction -> u (raw, unmasked).
// grid = (BN/64, 2 encoders). dyn LDS = 135424 B.
// ---------------------------------------------------------------------------
__global__ __launch_bounds__(512) void k_attn_u(
    const float* __restrict__ enc_e, const float* __restrict__ enc_s,
    const float* __restrict__ W1e, const float* __restrict__ W1s,
    const float* __restrict__ vte, const float* __restrict__ vts,
    const float* __restrict__ dt_e, const float* __restrict__ dt_s,
    float* __restrict__ u)
{
    extern __shared__ char smem_raw[];
    bf16x8* As  = (bf16x8*)smem_raw;                   // 4096 chunks: kg*64 + swiz(row)
    bf16x8* Bs  = (bf16x8*)(smem_raw + 65536);         // 2 x 2048 chunks: kc*256 + col
    float*  dts = (float*)(smem_raw + 131072);         // 512
    float*  vtl = dts + 512;                           // 512
    float*  uacc = vtl + 512;                          // 64

    const int e = blockIdx.y;
    const float* enc = e ? enc_s : enc_e;
    const float* W1  = e ? W1s : W1e;
    const float* vt  = e ? vts : vte;
    const float* dt  = e ? dt_s : dt_e;

    const int rowbase = blockIdx.x * 64;
    const int b = rowbase >> 7;
    const int t = threadIdx.x;
    const int w = t >> 6, lane = t & 63, g = lane >> 4, r = lane & 15;

    if (t < 64) uacc[t] = 0.f;
    dts[t] = dt[(size_t)b * 512 + t];
    vtl[t] = vt[t];

    // stage A: wave w loads rows w*8 .. w*8+7; lane covers k = lane*8..+7
    #pragma unroll
    for (int i = 0; i < 8; ++i) {
        int row = w * 8 + i;
        const float* src = enc + (size_t)(rowbase + row) * 512 + lane * 8;
        f32x4 x0 = *(const f32x4*)src;
        f32x4 x1 = *(const f32x4*)(src + 4);
        As[lane * 64 + (row ^ (lane & 15))] = pack8(x0, x1);
    }

    // B prefetch regs: 32 floats/thread per stage
    f32x4 p0[4], p1[4];
    {
        int cc = 0, kb = 0;
        #pragma unroll
        for (int jj = 0; jj < 4; ++jj) {
            int c = t + 512 * jj;
            int col = c >> 3, kc = c & 7;
            const float* src = W1 + (size_t)(cc * 256 + col) * 512 + kb * 64 + kc * 8;
            p0[jj] = *(const f32x4*)src;
            p1[jj] = *(const f32x4*)(src + 4);
        }
    }

    f32x4 acc[4][2];
    #pragma unroll
    for (int i = 0; i < 4; ++i) { acc[i][0] = (f32x4){0,0,0,0}; acc[i][1] = (f32x4){0,0,0,0}; }

    for (int s = 0; s < 16; ++s) {
        bf16x8* Bb = Bs + (s & 1) * 2048;
        #pragma unroll
        for (int jj = 0; jj < 4; ++jj) {
            int c = t + 512 * jj;
            int col = c >> 3, kc = c & 7;
            Bb[kc * 256 + col] = pack8(p0[jj], p1[jj]);
        }
        __syncthreads();
        if (s + 1 < 16) {
            int cc2 = (s + 1) >> 3, kb2 = (s + 1) & 7;
            #pragma unroll
            for (int jj = 0; jj < 4; ++jj) {
                int c = t + 512 * jj;
                int col = c >> 3, kc = c & 7;
                const float* src = W1 + (size_t)(cc2 * 256 + col) * 512 + kb2 * 64 + kc * 8;
                p0[jj] = *(const f32x4*)src;
                p1[jj] = *(const f32x4*)(src + 4);
            }
        }
        int kb = s & 7;
        #pragma unroll
        for (int kk = 0; kk < 2; ++kk) {
            int kg = kb * 8 + kk * 4 + g;
            bf16x8 bf0 = Bb[(kk * 4 + g) * 256 + w * 32 + r];
            bf16x8 bf1 = Bb[(kk * 4 + g) * 256 + w * 32 + 16 + r];
            #pragma unroll
            for (int i = 0; i < 4; ++i) {
                bf16x8 af = As[kg * 64 + (16 * i + (r ^ (kg & 15)))];
                acc[i][0] = mfma16(af, bf0, acc[i][0]);
                acc[i][1] = mfma16(af, bf1, acc[i][1]);
            }
        }
        if ((s & 7) == 7) {
            int cc = s >> 3;
            #pragma unroll
            for (int i = 0; i < 4; ++i) {
                float ps0 = 0.f, ps1 = 0.f, ps2 = 0.f, ps3 = 0.f;
                #pragma unroll
                for (int j = 0; j < 2; ++j) {
                    int col = cc * 256 + w * 32 + j * 16 + r;
                    float dv = dts[col], vv = vtl[col];
                    ps0 += vv * tanhf(acc[i][j][0] + dv);
                    ps1 += vv * tanhf(acc[i][j][1] + dv);
                    ps2 += vv * tanhf(acc[i][j][2] + dv);
                    ps3 += vv * tanhf(acc[i][j][3] + dv);
                }
                #pragma unroll
                for (int m = 1; m < 16; m <<= 1) {
                    ps0 += __shfl_xor(ps0, m);
                    ps1 += __shfl_xor(ps1, m);
                    ps2 += __shfl_xor(ps2, m);
                    ps3 += __shfl_xor(ps3, m);
                }
                if (r == 0) {
                    atomicAdd(&uacc[16 * i + 4 * g + 0], ps0);
                    atomicAdd(&uacc[16 * i + 4 * g + 1], ps1);
                    atomicAdd(&uacc[16 * i + 4 * g + 2], ps2);
                    atomicAdd(&uacc[16 * i + 4 * g + 3], ps3);
                }
                acc[i][0] = (f32x4){0,0,0,0};
                acc[i][1] = (f32x4){0,0,0,0};
            }
        }
    }
    __syncthreads();
    if (t < 64) u[(size_t)e * BN_ + rowbase + t] = uacc[t];
}

// ---------------------------------------------------------------------------
// K3: masked softmax over N for both encoders, plan softmax (f32 exact),
// ctx weighted sums, y_ctx assembly, plan -> d_out.  grid = (BS), 256 threads.
// ---------------------------------------------------------------------------
__global__ __launch_bounds__(256) void k_ctx(
    const float* __restrict__ u, const int* __restrict__ mask_e,
    const int* __restrict__ mask_s, const float* __restrict__ enc_e,
    const float* __restrict__ enc_s, const float* __restrict__ prev_h,
    const float* __restrict__ plan_W, const float* __restrict__ plan_b,
    const float* __restrict__ prev_y,
    float* __restrict__ y_ctx, float* __restrict__ plan_out)
{
    const int b = blockIdx.x;
    const int t = threadIdx.x;
    const int lane = t & 63, wid = t >> 6, half = t >> 7, n = t & 127;

    __shared__ float aw[2][128];
    __shared__ float red[16];
    __shared__ float planv[2];

    const int* mask = half ? mask_s : mask_e;
    float uv = u[(size_t)half * BN_ + b * 128 + n];
    bool msk = mask[b * 128 + n] != 0;
    float val = msk ? -3.4e38f : uv;

    float mx = val;
    #pragma unroll
    for (int m = 1; m < 64; m <<= 1) mx = fmaxf(mx, __shfl_xor(mx, m));
    if (lane == 0) red[wid] = mx;
    __syncthreads();
    mx = fmaxf(red[half * 2], red[half * 2 + 1]);
    float ex = msk ? 0.f : __expf(uv - mx);
    float sm = ex;
    #pragma unroll
    for (int m = 1; m < 64; m <<= 1) sm += __shfl_xor(sm, m);
    if (lane == 0) red[4 + wid] = sm;
    __syncthreads();
    sm = red[4 + half * 2] + red[4 + half * 2 + 1];
    aw[half][n] = ex / sm;

    // plan logits (exact f32)
    float p0 = 0.f, p1 = 0.f;
    for (int i = t; i < DD; i += 256) {
        float hv = prev_h[(size_t)b * DD + i];
        p0 += hv * plan_W[i];
        p1 += hv * plan_W[DD + i];
    }
    #pragma unroll
    for (int m = 1; m < 64; m <<= 1) { p0 += __shfl_xor(p0, m); p1 += __shfl_xor(p1, m); }
    if (lane == 0) { red[8 + wid] = p0; red[12 + wid] = p1; }
    __syncthreads();
    if (t == 0) {
        float l0 = red[8] + red[9] + red[10] + red[11] + plan_b[0];
        float l1 = red[12] + red[13] + red[14] + red[15] + plan_b[1];
        float mm = fmaxf(l0, l1);
        float e0 = __expf(l0 - mm), e1 = __expf(l1 - mm);
        float ss = e0 + e1;
        planv[0] = e0 / ss; planv[1] = e1 / ss;
        plan_out[b * 2 + 0] = planv[0];
        plan_out[b * 2 + 1] = planv[1];
    }
    __syncthreads();

    float pl0 = planv[0], pl1 = planv[1];
    #pragma unroll
    for (int cc = 0; cc < 2; ++cc) {
        int col = t + cc * 256;
        float ae = 0.f, as2 = 0.f;
        const float* pe = enc_e + (size_t)b * 128 * 512 + col;
        const float* ps = enc_s + (size_t)b * 128 * 512 + col;
        #pragma unroll 4
        for (int nn = 0; nn < 128; ++nn) {
            ae  += aw[0][nn] * pe[(size_t)nn * 512];
            as2 += aw[1][nn] * ps[(size_t)nn * 512];
        }
        float ctx = pl0 * ae + pl1 * as2;
        y_ctx[(size_t)b * 1024 + col] = prev_y[(size_t)b * 512 + col];
        y_ctx[(size_t)b * 1024 + 512 + col] = ctx;
    }
}

// ---------------------------------------------------------------------------
// K5: GRU gates, h_new -> ws and dec_hidden -> d_out. grid=(3, BS), 384 thr.
// ---------------------------------------------------------------------------
__global__ __launch_bounds__(384) void k_gru(
    const float* __restrict__ gx, const float* __restrict__ gh,
    const float* __restrict__ prev_h, float* __restrict__ h_new,
    float* __restrict__ out_hidden)
{
    int d = blockIdx.x * 384 + threadIdx.x;   // 0..1151
    int b = blockIdx.y;
    size_t o3 = (size_t)b * 3456;
    float xr = gx[o3 + d], xz = gx[o3 + 1152 + d], xn = gx[o3 + 2304 + d];
    float hr = gh[o3 + d], hz = gh[o3 + 1152 + d], hn = gh[o3 + 2304 + d];
    float rr = 1.f / (1.f + __expf(-(xr + hr)));
    float zz = 1.f / (1.f + __expf(-(xz + hz)));
    float nv = tanhf(xn + rr * hn);
    float hv = (1.f - zz) * nv + zz * prev_h[(size_t)b * DD + d];
    h_new[(size_t)b * DD + d] = hv;
    out_hidden[(size_t)b * DD + d] = hv;
}

// ---------------------------------------------------------------------------
extern "C" void kernel_launch(void* const* d_in, const int* in_sizes, int n_in,
                              void* d_out, int out_size, void* d_ws, size_t ws_size,
                              hipStream_t stream)
{
    const float* prev_y = (const float*)d_in[0];
    const float* prev_h = (const float*)d_in[1];
    const float* enc_e  = (const float*)d_in[2];
    const float* enc_s  = (const float*)d_in[3];
    // d_in[4] = z_sample (unused by reference)
    const int*   mask_e = (const int*)d_in[5];
    const int*   mask_s = (const int*)d_in[6];
    const float* W1e    = (const float*)d_in[7];
    const float* W2e    = (const float*)d_in[8];
    const float* vte    = (const float*)d_in[9];
    const float* W1s    = (const float*)d_in[10];
    const float* W2s    = (const float*)d_in[11];
    const float* vts    = (const float*)d_in[12];
    const float* plan_W = (const float*)d_in[13];
    const float* plan_b = (const float*)d_in[14];
    const float* Wc     = (const float*)d_in[15];
    const float* bc     = (const float*)d_in[16];
    const float* w_ih   = (const float*)d_in[17];
    const float* w_hh   = (const float*)d_in[18];
    const float* b_ih   = (const float*)d_in[19];
    const float* b_hh   = (const float*)d_in[20];
    const float* Wout   = (const float*)d_in[21];
    const float* bout   = (const float*)d_in[22];

    float* out = (float*)d_out;
    float* ws  = (float*)d_ws;
    float* dt_e  = ws;                  // 256*512
    float* dt_s  = dt_e + 131072;       // 256*512
    float* gh    = dt_s + 131072;       // 256*3456
    float* uu    = gh + 884736;         // 2*32768
    float* y_ctx = uu + 65536;          // 256*1024
    float* xx    = y_ctx + 262144;      // 256*512
    float* gx    = xx + 131072;         // 256*3456
    float* h_new = gx + 884736;         // 256*1152

    float* dec_out  = out;              // 256*32000
    float* dec_hid  = out + 8192000;    // 256*1152
    float* plan_out = out + 8486912;    // 256*2

    // K1: dt_e, dt_s, gh
    k_prevh<<<dim3(70, 4), 256, 0, stream>>>(prev_h, W2e, W2s, w_hh, b_hh,
                                             dt_e, dt_s, gh);

    // K2: attention logits u (both encoders)
    (void)hipFuncSetAttribute((const void*)k_attn_u,
                              hipFuncAttributeMaxDynamicSharedMemorySize, 143360);
    k_attn_u<<<dim3(BN_ / 64, 2), 512, 135424, stream>>>(
        enc_e, enc_s, W1e, W1s, vte, vts, dt_e, dt_s, uu);

    // K3: softmax + ctx + plan + y_ctx
    k_ctx<<<dim3(BS_), 256, 0, stream>>>(uu, mask_e, mask_s, enc_e, enc_s,
                                         prev_h, plan_W, plan_b, prev_y,
                                         y_ctx, plan_out);

    // K4a: x = y_ctx @ Wc^T + bc
    k_gemm_bias<<<dim3(8, 4), 256, 0, stream>>>(y_ctx, Wc, bc, xx, 1024, 512);
    // K4b: gx = x @ w_ih^T + b_ih
    k_gemm_bias<<<dim3(54, 4), 256, 0, stream>>>(xx, w_ih, b_ih, gx, 512, 3456);

    // K5: GRU
    k_gru<<<dim3(3, BS_), 384, 0, stream>>>(gx, gh, prev_h, h_new, dec_hid);

    // K6: dec_output = h_new @ Wout^T + bout
    k_gemm_bias<<<dim3(500, 4), 256, 0, stream>>>(h_new, Wout, bout, dec_out,
                                                  1152, 32000);
}

// Round 2
// 575.047 us; speedup vs baseline: 1.1162x; 1.1162x over previous
//
#include <hip/hip_runtime.h>
#include <stdint.h>
#include <math.h>

// Problem dims
#define BS_  256
#define NSEQ 128
#define HH   512
#define DD   1152      // 2H + Z
#define VV   32000
#define BN_  (BS_*NSEQ)  // 32768

typedef float  f32x4  __attribute__((ext_vector_type(4)));
typedef __bf16 bf16x8 __attribute__((ext_vector_type(8)));

__device__ __forceinline__ f32x4 mfma16(bf16x8 a, bf16x8 b, f32x4 c) {
    return __builtin_amdgcn_mfma_f32_16x16x32_bf16(a, b, c, 0, 0, 0);
}

__device__ __forceinline__ bf16x8 pack8(f32x4 a, f32x4 b) {
    bf16x8 v;
    v[0] = (__bf16)a[0]; v[1] = (__bf16)a[1]; v[2] = (__bf16)a[2]; v[3] = (__bf16)a[3];
    v[4] = (__bf16)b[0]; v[5] = (__bf16)b[1]; v[6] = (__bf16)b[2]; v[7] = (__bf16)b[3];
    return v;
}

__device__ __forceinline__ float tanh_fast(float x) {
    // 1 - 2/(e^{2x}+1); exp overflow -> 1.0, underflow -> -1.0 (no NaN)
    float e = __expf(2.f * x);
    return 1.f - __fdividef(2.f, e + 1.f);
}

// ---------------------------------------------------------------------------
// 128x128-tile MFMA GEMM: C[M,N] = A[M,K]*B[N,K]^T + bias (f32 mem, bf16 MFMA)
// 256 thr = 4 waves in 2x2; wave tile 64x64 = 4x4 MFMA tiles.
// LDS: XOR-swizzled chunk layout (2-way max bank aliasing = free).
// grid = (M/128, N/128); consecutive x-blocks share the B tile (L2/L3 dedup).
// ---------------------------------------------------------------------------
__global__ __launch_bounds__(256) void k_tile128(
    const float* __restrict__ A, const float* __restrict__ B,
    const float* __restrict__ bias, float* __restrict__ C,
    int K, int ldc)
{
    const int rb = blockIdx.x * 128;
    const int cb = blockIdx.y * 128;
    const int t = threadIdx.x;
    const int w = t >> 6, wr = w >> 1, wc = w & 1;
    const int lane = t & 63, g = lane >> 4, r = lane & 15;
    const int s_row = t >> 1, s_h = t & 1;

    __shared__ bf16x8 sm[2][2][512];   // [buf][A/B][swizzled chunk]

    const float* Ap = A + (size_t)(rb + s_row) * K + s_h * 16;
    const float* Bp = B + (size_t)(cb + s_row) * K + s_h * 16;

    const int kg0 = 2 * s_h, kg1 = 2 * s_h + 1;
    const int swz0 = kg0 * 128 + ((s_row & 112) | ((s_row ^ (kg0 << 2)) & 15));
    const int swz1 = kg1 * 128 + ((s_row & 112) | ((s_row ^ (kg1 << 2)) & 15));

    int ai[4], bi[4];
    #pragma unroll
    for (int i = 0; i < 4; ++i) {
        ai[i] = g * 128 + wr * 64 + i * 16 + ((r ^ (g << 2)) & 15);
        bi[i] = g * 128 + wc * 64 + i * 16 + ((r ^ (g << 2)) & 15);
    }

    const int KS = K >> 5;
    f32x4 pa0 = ((const f32x4*)Ap)[0], pa1 = ((const f32x4*)Ap)[1],
          pa2 = ((const f32x4*)Ap)[2], pa3 = ((const f32x4*)Ap)[3];
    f32x4 pb0 = ((const f32x4*)Bp)[0], pb1 = ((const f32x4*)Bp)[1],
          pb2 = ((const f32x4*)Bp)[2], pb3 = ((const f32x4*)Bp)[3];

    f32x4 acc[4][4];
    #pragma unroll
    for (int i = 0; i < 4; ++i)
        #pragma unroll
        for (int j = 0; j < 4; ++j) acc[i][j] = (f32x4){0.f, 0.f, 0.f, 0.f};

    for (int kb = 0; kb < KS; ++kb) {
        const int buf = kb & 1;
        sm[buf][0][swz0] = pack8(pa0, pa1);
        sm[buf][0][swz1] = pack8(pa2, pa3);
        sm[buf][1][swz0] = pack8(pb0, pb1);
        sm[buf][1][swz1] = pack8(pb2, pb3);
        __syncthreads();
        if (kb + 1 < KS) {
            const float* a2 = Ap + (kb + 1) * 32;
            const float* b2 = Bp + (kb + 1) * 32;
            pa0 = ((const f32x4*)a2)[0]; pa1 = ((const f32x4*)a2)[1];
            pa2 = ((const f32x4*)a2)[2]; pa3 = ((const f32x4*)a2)[3];
            pb0 = ((const f32x4*)b2)[0]; pb1 = ((const f32x4*)b2)[1];
            pb2 = ((const f32x4*)b2)[2]; pb3 = ((const f32x4*)b2)[3];
        }
        bf16x8 af[4], bfr[4];
        #pragma unroll
        for (int i = 0; i < 4; ++i) af[i]  = sm[buf][0][ai[i]];
        #pragma unroll
        for (int j = 0; j < 4; ++j) bfr[j] = sm[buf][1][bi[j]];
        #pragma unroll
        for (int i = 0; i < 4; ++i)
            #pragma unroll
            for (int j = 0; j < 4; ++j)
                acc[i][j] = mfma16(af[i], bfr[j], acc[i][j]);
    }

    #pragma unroll
    for (int j = 0; j < 4; ++j) {
        const int col = cb + wc * 64 + j * 16 + r;
        const float bv = bias ? bias[col] : 0.f;
        #pragma unroll
        for (int i = 0; i < 4; ++i) {
            #pragma unroll
            for (int q = 0; q < 4; ++q) {
                const int row = rb + wr * 64 + i * 16 + g * 4 + q;
                C[(size_t)row * ldc + col] = acc[i][j][q] + bv;
            }
        }
    }
}

// ---------------------------------------------------------------------------
// K1: prev_h (256x1152) against virtual concat [W2e(512) | W2s(512) | w_hh(3456)]
// 64x64 tiles (small GEMM, needs block-count). grid = (70, 4).
// ---------------------------------------------------------------------------
__global__ __launch_bounds__(256) void k_prevh(
    const float* __restrict__ prev_h, const float* __restrict__ W2e,
    const float* __restrict__ W2s, const float* __restrict__ w_hh,
    const float* __restrict__ b_hh,
    float* __restrict__ dt_e, float* __restrict__ dt_s, float* __restrict__ gh)
{
    const int cb = blockIdx.x * 64;
    const int rb = blockIdx.y * 64;
    const int t  = threadIdx.x;
    const int w = t >> 6, lane = t & 63, g = lane >> 4, r = lane & 15;
    const int s_row = t >> 2, s_kc = t & 3;
    const int K = DD;

    __shared__ bf16x8 sm[2][2][256];

    const float* Ap = prev_h + (size_t)(rb + s_row) * K + s_kc * 8;
    const float* Bp;
    {
        int brow = cb + s_row;
        if (cb < 512)        Bp = W2e + (size_t)brow * K;
        else if (cb < 1024)  Bp = W2s + (size_t)(brow - 512) * K;
        else                 Bp = w_hh + (size_t)(brow - 1024) * K;
        Bp += s_kc * 8;
    }

    const int KS = K >> 5;   // 36
    f32x4 pa0 = *(const f32x4*)Ap, pa1 = *(const f32x4*)(Ap + 4);
    f32x4 pb0 = *(const f32x4*)Bp, pb1 = *(const f32x4*)(Bp + 4);

    f32x4 acc[4] = {{0,0,0,0},{0,0,0,0},{0,0,0,0},{0,0,0,0}};

    for (int kb = 0; kb < KS; ++kb) {
        sm[kb & 1][0][s_kc * 64 + s_row] = pack8(pa0, pa1);
        sm[kb & 1][1][s_kc * 64 + s_row] = pack8(pb0, pb1);
        __syncthreads();
        if (kb + 1 < KS) {
            const float* a2 = Ap + (kb + 1) * 32;
            const float* b2 = Bp + (kb + 1) * 32;
            pa0 = *(const f32x4*)a2; pa1 = *(const f32x4*)(a2 + 4);
            pb0 = *(const f32x4*)b2; pb1 = *(const f32x4*)(b2 + 4);
        }
        bf16x8 af = sm[kb & 1][0][g * 64 + w * 16 + r];
        #pragma unroll
        for (int j = 0; j < 4; ++j) {
            bf16x8 bf = sm[kb & 1][1][g * 64 + j * 16 + r];
            acc[j] = mfma16(af, bf, acc[j]);
        }
    }

    #pragma unroll
    for (int j = 0; j < 4; ++j) {
        int col = cb + j * 16 + r;
        #pragma unroll
        for (int q = 0; q < 4; ++q) {
            int row = rb + w * 16 + g * 4 + q;
            float v = acc[j][q];
            if (cb < 512)       dt_e[(size_t)row * 512 + col] = v;
            else if (cb < 1024) dt_s[(size_t)row * 512 + (col - 512)] = v;
            else {
                int c0 = col - 1024;
                gh[(size_t)row * 3456 + c0] = v + b_hh[c0];
            }
        }
    }
}

// ---------------------------------------------------------------------------
// K2: attention logits u[b,n] = sum_k vt[k]*tanh(et[b,n,k] + dt[b,k]).
// One block per (batch b, encoder e): 128 enc rows x 512 et-cols in 4 col
// phases of 128 (enc tile re-read hits same-CU L2). m97-shape inner loop +
// fused tanh/vt epilogue with shfl reduction. grid = (256, 2), 256 thr.
// ---------------------------------------------------------------------------
__global__ __launch_bounds__(256) void k_attn(
    const float* __restrict__ enc_e, const float* __restrict__ enc_s,
    const float* __restrict__ W1e, const float* __restrict__ W1s,
    const float* __restrict__ vte, const float* __restrict__ vts,
    const float* __restrict__ dt_e, const float* __restrict__ dt_s,
    float* __restrict__ u)
{
    const int b = blockIdx.x;
    const int e = blockIdx.y;
    const float* enc = e ? enc_s : enc_e;
    const float* W1  = e ? W1s  : W1e;
    const float* vt  = e ? vts  : vte;
    const float* dt  = e ? dt_s : dt_e;

    __shared__ bf16x8 sm[2][2][512];   // 32 KB
    __shared__ float uacc[128];

    const int t = threadIdx.x;
    const int w = t >> 6, wr = w >> 1, wc = w & 1;
    const int lane = t & 63, g = lane >> 4, r = lane & 15;
    const int s_row = t >> 1, s_h = t & 1;

    if (t < 128) uacc[t] = 0.f;

    const int kg0 = 2 * s_h, kg1 = 2 * s_h + 1;
    const int swz0 = kg0 * 128 + ((s_row & 112) | ((s_row ^ (kg0 << 2)) & 15));
    const int swz1 = kg1 * 128 + ((s_row & 112) | ((s_row ^ (kg1 << 2)) & 15));

    int ai[4], bi[4];
    #pragma unroll
    for (int i = 0; i < 4; ++i) {
        ai[i] = g * 128 + wr * 64 + i * 16 + ((r ^ (g << 2)) & 15);
        bi[i] = g * 128 + wc * 64 + i * 16 + ((r ^ (g << 2)) & 15);
    }

    const float* Abase = enc + (size_t)(b * 128 + s_row) * 512 + s_h * 16;

    f32x4 pa0, pa1, pa2, pa3, pb0, pb1, pb2, pb3;
    {
        const float* ap = Abase;
        const float* bp = W1 + (size_t)s_row * 512 + s_h * 16;
        pa0 = ((const f32x4*)ap)[0]; pa1 = ((const f32x4*)ap)[1];
        pa2 = ((const f32x4*)ap)[2]; pa3 = ((const f32x4*)ap)[3];
        pb0 = ((const f32x4*)bp)[0]; pb1 = ((const f32x4*)bp)[1];
        pb2 = ((const f32x4*)bp)[2]; pb3 = ((const f32x4*)bp)[3];
    }

    for (int nc = 0; nc < 4; ++nc) {
        f32x4 acc[4][4];
        #pragma unroll
        for (int i = 0; i < 4; ++i)
            #pragma unroll
            for (int j = 0; j < 4; ++j) acc[i][j] = (f32x4){0.f, 0.f, 0.f, 0.f};

        for (int kb = 0; kb < 16; ++kb) {
            const int buf = kb & 1;
            sm[buf][0][swz0] = pack8(pa0, pa1);
            sm[buf][0][swz1] = pack8(pa2, pa3);
            sm[buf][1][swz0] = pack8(pb0, pb1);
            sm[buf][1][swz1] = pack8(pb2, pb3);
            __syncthreads();

            int nnc = nc, nkb = kb + 1;
            if (nkb == 16) { nnc = nc + 1; nkb = 0; }
            if (nnc < 4) {
                const float* ap = Abase + nkb * 32;
                const float* bp = W1 + (size_t)(nnc * 128 + s_row) * 512 + nkb * 32 + s_h * 16;
                pa0 = ((const f32x4*)ap)[0]; pa1 = ((const f32x4*)ap)[1];
                pa2 = ((const f32x4*)ap)[2]; pa3 = ((const f32x4*)ap)[3];
                pb0 = ((const f32x4*)bp)[0]; pb1 = ((const f32x4*)bp)[1];
                pb2 = ((const f32x4*)bp)[2]; pb3 = ((const f32x4*)bp)[3];
            }

            bf16x8 af[4], bfr[4];
            #pragma unroll
            for (int i = 0; i < 4; ++i) af[i]  = sm[buf][0][ai[i]];
            #pragma unroll
            for (int j = 0; j < 4; ++j) bfr[j] = sm[buf][1][bi[j]];
            #pragma unroll
            for (int i = 0; i < 4; ++i)
                #pragma unroll
                for (int j = 0; j < 4; ++j)
                    acc[i][j] = mfma16(af[i], bfr[j], acc[i][j]);
        }

        // fused epilogue: u_row += sum_col vt[col]*tanh(et + dt[col])
        float dv[4], vv[4];
        #pragma unroll
        for (int j = 0; j < 4; ++j) {
            int col = nc * 128 + wc * 64 + j * 16 + r;
            dv[j] = dt[(size_t)b * 512 + col];
            vv[j] = vt[col];
        }
        #pragma unroll
        for (int i = 0; i < 4; ++i) {
            #pragma unroll
            for (int q = 0; q < 4; ++q) {
                float s = 0.f;
                #pragma unroll
                for (int j = 0; j < 4; ++j)
                    s += vv[j] * tanh_fast(acc[i][j][q] + dv[j]);
                #pragma unroll
                for (int m = 1; m < 16; m <<= 1) s += __shfl_xor(s, m);
                if (r == 0) atomicAdd(&uacc[wr * 64 + i * 16 + g * 4 + q], s);
            }
        }
    }
    __syncthreads();
    if (t < 128) u[(size_t)e * BN_ + b * 128 + t] = uacc[t];
}

// ---------------------------------------------------------------------------
// K3: masked softmax over N, plan softmax, ctx weighted sums, y_ctx assembly.
// grid = (256 batches, 2 col-halves), 256 threads.
// ---------------------------------------------------------------------------
__global__ __launch_bounds__(256) void k_ctx(
    const float* __restrict__ u, const int* __restrict__ mask_e,
    const int* __restrict__ mask_s, const float* __restrict__ enc_e,
    const float* __restrict__ enc_s, const float* __restrict__ prev_h,
    const float* __restrict__ plan_W, const float* __restrict__ plan_b,
    const float* __restrict__ prev_y,
    float* __restrict__ y_ctx, float* __restrict__ plan_out)
{
    const int b = blockIdx.x;
    const int t = threadIdx.x;
    const int lane = t & 63, wid = t >> 6, half = t >> 7, n = t & 127;

    __shared__ float aw[2][128];
    __shared__ float red[16];
    __shared__ float planv[2];

    const int* mask = half ? mask_s : mask_e;
    float uv = u[(size_t)half * BN_ + b * 128 + n];
    bool msk = mask[b * 128 + n] != 0;
    float val = msk ? -3.4e38f : uv;

    float mx = val;
    #pragma unroll
    for (int m = 1; m < 64; m <<= 1) mx = fmaxf(mx, __shfl_xor(mx, m));
    if (lane == 0) red[wid] = mx;
    __syncthreads();
    mx = fmaxf(red[half * 2], red[half * 2 + 1]);
    float ex = msk ? 0.f : __expf(uv - mx);
    float sm = ex;
    #pragma unroll
    for (int m = 1; m < 64; m <<= 1) sm += __shfl_xor(sm, m);
    if (lane == 0) red[4 + wid] = sm;
    __syncthreads();
    sm = red[4 + half * 2] + red[4 + half * 2 + 1];
    aw[half][n] = ex / sm;

    // plan logits (exact f32)
    float p0 = 0.f, p1 = 0.f;
    for (int i = t; i < DD; i += 256) {
        float hv = prev_h[(size_t)b * DD + i];
        p0 += hv * plan_W[i];
        p1 += hv * plan_W[DD + i];
    }
    #pragma unroll
    for (int m = 1; m < 64; m <<= 1) { p0 += __shfl_xor(p0, m); p1 += __shfl_xor(p1, m); }
    if (lane == 0) { red[8 + wid] = p0; red[12 + wid] = p1; }
    __syncthreads();
    if (t == 0) {
        float l0 = red[8] + red[9] + red[10] + red[11] + plan_b[0];
        float l1 = red[12] + red[13] + red[14] + red[15] + plan_b[1];
        float mm = fmaxf(l0, l1);
        float e0 = __expf(l0 - mm), e1 = __expf(l1 - mm);
        float ss = e0 + e1;
        planv[0] = e0 / ss; planv[1] = e1 / ss;
        plan_out[b * 2 + 0] = planv[0];
        plan_out[b * 2 + 1] = planv[1];
    }
    __syncthreads();

    float pl0 = planv[0], pl1 = planv[1];
    int col = blockIdx.y * 256 + t;
    float ae = 0.f, as2 = 0.f;
    const float* pe = enc_e + (size_t)b * 128 * 512 + col;
    const float* ps = enc_s + (size_t)b * 128 * 512 + col;
    #pragma unroll 8
    for (int nn = 0; nn < 128; ++nn) {
        ae  += aw[0][nn] * pe[(size_t)nn * 512];
        as2 += aw[1][nn] * ps[(size_t)nn * 512];
    }
    float ctx = pl0 * ae + pl1 * as2;
    y_ctx[(size_t)b * 1024 + col] = prev_y[(size_t)b * 512 + col];
    y_ctx[(size_t)b * 1024 + 512 + col] = ctx;
}

// ---------------------------------------------------------------------------
// K4a: 64x64-tile GEMM (kept for the small x = y_ctx@Wc^T GEMM)
// ---------------------------------------------------------------------------
__global__ __launch_bounds__(256) void k_gemm_bias(
    const float* __restrict__ A, const float* __restrict__ B,
    const float* __restrict__ bias, float* __restrict__ C,
    int K, int ldc)
{
    const int cb = blockIdx.x * 64;
    const int rb = blockIdx.y * 64;
    const int t  = threadIdx.x;
    const int w = t >> 6, lane = t & 63, g = lane >> 4, r = lane & 15;
    const int s_row = t >> 2, s_kc = t & 3;

    __shared__ bf16x8 sm[2][2][256];

    const float* Ap = A + (size_t)(rb + s_row) * K + s_kc * 8;
    const float* Bp = B + (size_t)(cb + s_row) * K + s_kc * 8;

    const int KS = K >> 5;
    f32x4 pa0 = *(const f32x4*)Ap, pa1 = *(const f32x4*)(Ap + 4);
    f32x4 pb0 = *(const f32x4*)Bp, pb1 = *(const f32x4*)(Bp + 4);

    f32x4 acc[4] = {{0,0,0,0},{0,0,0,0},{0,0,0,0},{0,0,0,0}};

    for (int kb = 0; kb < KS; ++kb) {
        sm[kb & 1][0][s_kc * 64 + s_row] = pack8(pa0, pa1);
        sm[kb & 1][1][s_kc * 64 + s_row] = pack8(pb0, pb1);
        __syncthreads();
        if (kb + 1 < KS) {
            const float* a2 = Ap + (kb + 1) * 32;
            const float* b2 = Bp + (kb + 1) * 32;
            pa0 = *(const f32x4*)a2; pa1 = *(const f32x4*)(a2 + 4);
            pb0 = *(const f32x4*)b2; pb1 = *(const f32x4*)(b2 + 4);
        }
        bf16x8 af = sm[kb & 1][0][g * 64 + w * 16 + r];
        #pragma unroll
        for (int j = 0; j < 4; ++j) {
            bf16x8 bf = sm[kb & 1][1][g * 64 + j * 16 + r];
            acc[j] = mfma16(af, bf, acc[j]);
        }
    }
    #pragma unroll
    for (int j = 0; j < 4; ++j) {
        int col = cb + j * 16 + r;
        float bv = bias ? bias[col] : 0.f;
        #pragma unroll
        for (int q = 0; q < 4; ++q) {
            int row = rb + w * 16 + g * 4 + q;
            C[(size_t)row * ldc + col] = acc[j][q] + bv;
        }
    }
}

// ---------------------------------------------------------------------------
// K5: GRU gates. grid=(3, BS), 384 thr.
// ---------------------------------------------------------------------------
__global__ __launch_bounds__(384) void k_gru(
    const float* __restrict__ gx, const float* __restrict__ gh,
    const float* __restrict__ prev_h, float* __restrict__ h_new,
    float* __restrict__ out_hidden)
{
    int d = blockIdx.x * 384 + threadIdx.x;   // 0..1151
    int b = blockIdx.y;
    size_t o3 = (size_t)b * 3456;
    float xr = gx[o3 + d], xz = gx[o3 + 1152 + d], xn = gx[o3 + 2304 + d];
    float hr = gh[o3 + d], hz = gh[o3 + 1152 + d], hn = gh[o3 + 2304 + d];
    float rr = 1.f / (1.f + __expf(-(xr + hr)));
    float zz = 1.f / (1.f + __expf(-(xz + hz)));
    float nv = tanhf(xn + rr * hn);
    float hv = (1.f - zz) * nv + zz * prev_h[(size_t)b * DD + d];
    h_new[(size_t)b * DD + d] = hv;
    out_hidden[(size_t)b * DD + d] = hv;
}

// ---------------------------------------------------------------------------
extern "C" void kernel_launch(void* const* d_in, const int* in_sizes, int n_in,
                              void* d_out, int out_size, void* d_ws, size_t ws_size,
                              hipStream_t stream)
{
    const float* prev_y = (const float*)d_in[0];
    const float* prev_h = (const float*)d_in[1];
    const float* enc_e  = (const float*)d_in[2];
    const float* enc_s  = (const float*)d_in[3];
    const int*   mask_e = (const int*)d_in[5];
    const int*   mask_s = (const int*)d_in[6];
    const float* W1e    = (const float*)d_in[7];
    const float* W2e    = (const float*)d_in[8];
    const float* vte    = (const float*)d_in[9];
    const float* W1s    = (const float*)d_in[10];
    const float* W2s    = (const float*)d_in[11];
    const float* vts    = (const float*)d_in[12];
    const float* plan_W = (const float*)d_in[13];
    const float* plan_b = (const float*)d_in[14];
    const float* Wc     = (const float*)d_in[15];
    const float* bc     = (const float*)d_in[16];
    const float* w_ih   = (const float*)d_in[17];
    const float* w_hh   = (const float*)d_in[18];
    const float* b_ih   = (const float*)d_in[19];
    const float* b_hh   = (const float*)d_in[20];
    const float* Wout   = (const float*)d_in[21];
    const float* bout   = (const float*)d_in[22];

    float* out = (float*)d_out;
    float* ws  = (float*)d_ws;
    float* dt_e  = ws;                  // 256*512
    float* dt_s  = dt_e + 131072;       // 256*512
    float* gh    = dt_s + 131072;       // 256*3456
    float* uu    = gh + 884736;         // 2*32768
    float* y_ctx = uu + 65536;          // 256*1024
    float* xx    = y_ctx + 262144;      // 256*512
    float* gx    = xx + 131072;         // 256*3456
    float* h_new = gx + 884736;         // 256*1152

    float* dec_out  = out;              // 256*32000
    float* dec_hid  = out + 8192000;    // 256*1152
    float* plan_out = out + 8486912;    // 256*2

    // K1: dt_e, dt_s, gh
    k_prevh<<<dim3(70, 4), 256, 0, stream>>>(prev_h, W2e, W2s, w_hh, b_hh,
                                             dt_e, dt_s, gh);

    // K2: attention logits u (both encoders)
    k_attn<<<dim3(BS_, 2), 256, 0, stream>>>(
        enc_e, enc_s, W1e, W1s, vte, vts, dt_e, dt_s, uu);

    // K3: softmax + ctx + plan + y_ctx
    k_ctx<<<dim3(BS_, 2), 256, 0, stream>>>(uu, mask_e, mask_s, enc_e, enc_s,
                                            prev_h, plan_W, plan_b, prev_y,
                                            y_ctx, plan_out);

    // K4a: x = y_ctx @ Wc^T + bc
    k_gemm_bias<<<dim3(8, 4), 256, 0, stream>>>(y_ctx, Wc, bc, xx, 1024, 512);
    // K4b: gx = x @ w_ih^T + b_ih   (128-tile: w_ih streamed once)
    k_tile128<<<dim3(2, 27), 256, 0, stream>>>(xx, w_ih, b_ih, gx, 512, 3456);

    // K5: GRU
    k_gru<<<dim3(3, BS_), 384, 0, stream>>>(gx, gh, prev_h, h_new, dec_hid);

    // K6: dec_output = h_new @ Wout^T + bout  (128-tile: Wout streamed ~once)
    k_tile128<<<dim3(2, 250), 256, 0, stream>>>(h_new, Wout, bout, dec_out,
                                                1152, 32000);
}

// Round 3
// 554.562 us; speedup vs baseline: 1.1574x; 1.0369x over previous
//
#include <hip/hip_runtime.h>
#include <stdint.h>
#include <math.h>

// Problem dims
#define BS_  256
#define NSEQ 128
#define HH   512
#define DD   1152      // 2H + Z
#define VV   32000
#define BN_  (BS_*NSEQ)  // 32768

typedef float  f32x4  __attribute__((ext_vector_type(4)));
typedef __bf16 bf16x8 __attribute__((ext_vector_type(8)));

__device__ __forceinline__ f32x4 mfma16(bf16x8 a, bf16x8 b, f32x4 c) {
    return __builtin_amdgcn_mfma_f32_16x16x32_bf16(a, b, c, 0, 0, 0);
}

__device__ __forceinline__ bf16x8 pack8(f32x4 a, f32x4 b) {
    bf16x8 v;
    v[0] = (__bf16)a[0]; v[1] = (__bf16)a[1]; v[2] = (__bf16)a[2]; v[3] = (__bf16)a[3];
    v[4] = (__bf16)b[0]; v[5] = (__bf16)b[1]; v[6] = (__bf16)b[2]; v[7] = (__bf16)b[3];
    return v;
}

__device__ __forceinline__ float tanh_fast(float x) {
    float e = __expf(2.f * x);
    return 1.f - __fdividef(2.f, e + 1.f);
}

// ---------------------------------------------------------------------------
// 128x128-tile MFMA GEMM core (used by k_tile128 / k_vocab / k_attn).
// 256 thr = 4 waves 2x2, wave tile 64x64, XOR-swizzled LDS.
// ---------------------------------------------------------------------------
__global__ __launch_bounds__(256) void k_tile128(
    const float* __restrict__ A, const float* __restrict__ B,
    const float* __restrict__ bias, float* __restrict__ C,
    int K, int ldc)
{
    const int rb = blockIdx.x * 128;
    const int cb = blockIdx.y * 128;
    const int t = threadIdx.x;
    const int w = t >> 6, wr = w >> 1, wc = w & 1;
    const int lane = t & 63, g = lane >> 4, r = lane & 15;
    const int s_row = t >> 1, s_h = t & 1;

    __shared__ bf16x8 sm[2][2][512];

    const float* Ap = A + (size_t)(rb + s_row) * K + s_h * 16;
    const float* Bp = B + (size_t)(cb + s_row) * K + s_h * 16;

    const int kg0 = 2 * s_h, kg1 = 2 * s_h + 1;
    const int swz0 = kg0 * 128 + ((s_row & 112) | ((s_row ^ (kg0 << 2)) & 15));
    const int swz1 = kg1 * 128 + ((s_row & 112) | ((s_row ^ (kg1 << 2)) & 15));

    int ai[4], bi[4];
    #pragma unroll
    for (int i = 0; i < 4; ++i) {
        ai[i] = g * 128 + wr * 64 + i * 16 + ((r ^ (g << 2)) & 15);
        bi[i] = g * 128 + wc * 64 + i * 16 + ((r ^ (g << 2)) & 15);
    }

    const int KS = K >> 5;
    f32x4 pa0 = ((const f32x4*)Ap)[0], pa1 = ((const f32x4*)Ap)[1],
          pa2 = ((const f32x4*)Ap)[2], pa3 = ((const f32x4*)Ap)[3];
    f32x4 pb0 = ((const f32x4*)Bp)[0], pb1 = ((const f32x4*)Bp)[1],
          pb2 = ((const f32x4*)Bp)[2], pb3 = ((const f32x4*)Bp)[3];

    f32x4 acc[4][4];
    #pragma unroll
    for (int i = 0; i < 4; ++i)
        #pragma unroll
        for (int j = 0; j < 4; ++j) acc[i][j] = (f32x4){0.f, 0.f, 0.f, 0.f};

    for (int kb = 0; kb < KS; ++kb) {
        const int buf = kb & 1;
        sm[buf][0][swz0] = pack8(pa0, pa1);
        sm[buf][0][swz1] = pack8(pa2, pa3);
        sm[buf][1][swz0] = pack8(pb0, pb1);
        sm[buf][1][swz1] = pack8(pb2, pb3);
        __syncthreads();
        if (kb + 1 < KS) {
            const float* a2 = Ap + (kb + 1) * 32;
            const float* b2 = Bp + (kb + 1) * 32;
            pa0 = ((const f32x4*)a2)[0]; pa1 = ((const f32x4*)a2)[1];
            pa2 = ((const f32x4*)a2)[2]; pa3 = ((const f32x4*)a2)[3];
            pb0 = ((const f32x4*)b2)[0]; pb1 = ((const f32x4*)b2)[1];
            pb2 = ((const f32x4*)b2)[2]; pb3 = ((const f32x4*)b2)[3];
        }
        bf16x8 af[4], bfr[4];
        #pragma unroll
        for (int i = 0; i < 4; ++i) af[i]  = sm[buf][0][ai[i]];
        #pragma unroll
        for (int j = 0; j < 4; ++j) bfr[j] = sm[buf][1][bi[j]];
        #pragma unroll
        for (int i = 0; i < 4; ++i)
            #pragma unroll
            for (int j = 0; j < 4; ++j)
                acc[i][j] = mfma16(af[i], bfr[j], acc[i][j]);
    }

    #pragma unroll
    for (int j = 0; j < 4; ++j) {
        const int col = cb + wc * 64 + j * 16 + r;
        const float bv = bias ? bias[col] : 0.f;
        #pragma unroll
        for (int i = 0; i < 4; ++i) {
            #pragma unroll
            for (int q = 0; q < 4; ++q) {
                const int row = rb + wr * 64 + i * 16 + g * 4 + q;
                C[(size_t)row * ldc + col] = acc[i][j][q] + bv;
            }
        }
    }
}

// ---------------------------------------------------------------------------
// Vocab GEMM: same core, XCD-swizzled grid so the two 128-row blocks sharing
// a Wout col tile land on the same XCD (L2 dedup). grid = 512 (12 idle).
// ---------------------------------------------------------------------------
__global__ __launch_bounds__(256) void k_vocab(
    const float* __restrict__ A, const float* __restrict__ B,
    const float* __restrict__ bias, float* __restrict__ C,
    int K, int ldc)
{
    const int L = blockIdx.x;
    const int p  = (L & 7) + ((L >> 4) << 3);   // col tile 0..255
    const int rr = (L >> 3) & 1;                // row tile 0..1
    if (p >= 250) return;
    const int rb = rr * 128;
    const int cb = p * 128;

    const int t = threadIdx.x;
    const int w = t >> 6, wr = w >> 1, wc = w & 1;
    const int lane = t & 63, g = lane >> 4, r = lane & 15;
    const int s_row = t >> 1, s_h = t & 1;

    __shared__ bf16x8 sm[2][2][512];

    const float* Ap = A + (size_t)(rb + s_row) * K + s_h * 16;
    const float* Bp = B + (size_t)(cb + s_row) * K + s_h * 16;

    const int kg0 = 2 * s_h, kg1 = 2 * s_h + 1;
    const int swz0 = kg0 * 128 + ((s_row & 112) | ((s_row ^ (kg0 << 2)) & 15));
    const int swz1 = kg1 * 128 + ((s_row & 112) | ((s_row ^ (kg1 << 2)) & 15));

    int ai[4], bi[4];
    #pragma unroll
    for (int i = 0; i < 4; ++i) {
        ai[i] = g * 128 + wr * 64 + i * 16 + ((r ^ (g << 2)) & 15);
        bi[i] = g * 128 + wc * 64 + i * 16 + ((r ^ (g << 2)) & 15);
    }

    const int KS = K >> 5;
    f32x4 pa0 = ((const f32x4*)Ap)[0], pa1 = ((const f32x4*)Ap)[1],
          pa2 = ((const f32x4*)Ap)[2], pa3 = ((const f32x4*)Ap)[3];
    f32x4 pb0 = ((const f32x4*)Bp)[0], pb1 = ((const f32x4*)Bp)[1],
          pb2 = ((const f32x4*)Bp)[2], pb3 = ((const f32x4*)Bp)[3];

    f32x4 acc[4][4];
    #pragma unroll
    for (int i = 0; i < 4; ++i)
        #pragma unroll
        for (int j = 0; j < 4; ++j) acc[i][j] = (f32x4){0.f, 0.f, 0.f, 0.f};

    for (int kb = 0; kb < KS; ++kb) {
        const int buf = kb & 1;
        sm[buf][0][swz0] = pack8(pa0, pa1);
        sm[buf][0][swz1] = pack8(pa2, pa3);
        sm[buf][1][swz0] = pack8(pb0, pb1);
        sm[buf][1][swz1] = pack8(pb2, pb3);
        __syncthreads();
        if (kb + 1 < KS) {
            const float* a2 = Ap + (kb + 1) * 32;
            const float* b2 = Bp + (kb + 1) * 32;
            pa0 = ((const f32x4*)a2)[0]; pa1 = ((const f32x4*)a2)[1];
            pa2 = ((const f32x4*)a2)[2]; pa3 = ((const f32x4*)a2)[3];
            pb0 = ((const f32x4*)b2)[0]; pb1 = ((const f32x4*)b2)[1];
            pb2 = ((const f32x4*)b2)[2]; pb3 = ((const f32x4*)b2)[3];
        }
        bf16x8 af[4], bfr[4];
        #pragma unroll
        for (int i = 0; i < 4; ++i) af[i]  = sm[buf][0][ai[i]];
        #pragma unroll
        for (int j = 0; j < 4; ++j) bfr[j] = sm[buf][1][bi[j]];
        #pragma unroll
        for (int i = 0; i < 4; ++i)
            #pragma unroll
            for (int j = 0; j < 4; ++j)
                acc[i][j] = mfma16(af[i], bfr[j], acc[i][j]);
    }

    #pragma unroll
    for (int j = 0; j < 4; ++j) {
        const int col = cb + wc * 64 + j * 16 + r;
        const float bv = bias[col];
        #pragma unroll
        for (int i = 0; i < 4; ++i) {
            #pragma unroll
            for (int q = 0; q < 4; ++q) {
                const int row = rb + wr * 64 + i * 16 + g * 4 + q;
                C[(size_t)row * ldc + col] = acc[i][j][q] + bv;
            }
        }
    }
}

// ---------------------------------------------------------------------------
// K1: prev_h against virtual concat [W2e | W2s | w_hh], 64x64 tiles.
// ---------------------------------------------------------------------------
__global__ __launch_bounds__(256) void k_prevh(
    const float* __restrict__ prev_h, const float* __restrict__ W2e,
    const float* __restrict__ W2s, const float* __restrict__ w_hh,
    const float* __restrict__ b_hh,
    float* __restrict__ dt_e, float* __restrict__ dt_s, float* __restrict__ gh)
{
    const int cb = blockIdx.x * 64;
    const int rb = blockIdx.y * 64;
    const int t  = threadIdx.x;
    const int w = t >> 6, lane = t & 63, g = lane >> 4, r = lane & 15;
    const int s_row = t >> 2, s_kc = t & 3;
    const int K = DD;

    __shared__ bf16x8 sm[2][2][256];

    const float* Ap = prev_h + (size_t)(rb + s_row) * K + s_kc * 8;
    const float* Bp;
    {
        int brow = cb + s_row;
        if (cb < 512)        Bp = W2e + (size_t)brow * K;
        else if (cb < 1024)  Bp = W2s + (size_t)(brow - 512) * K;
        else                 Bp = w_hh + (size_t)(brow - 1024) * K;
        Bp += s_kc * 8;
    }

    const int KS = K >> 5;   // 36
    f32x4 pa0 = *(const f32x4*)Ap, pa1 = *(const f32x4*)(Ap + 4);
    f32x4 pb0 = *(const f32x4*)Bp, pb1 = *(const f32x4*)(Bp + 4);

    f32x4 acc[4] = {{0,0,0,0},{0,0,0,0},{0,0,0,0},{0,0,0,0}};

    for (int kb = 0; kb < KS; ++kb) {
        sm[kb & 1][0][s_kc * 64 + s_row] = pack8(pa0, pa1);
        sm[kb & 1][1][s_kc * 64 + s_row] = pack8(pb0, pb1);
        __syncthreads();
        if (kb + 1 < KS) {
            const float* a2 = Ap + (kb + 1) * 32;
            const float* b2 = Bp + (kb + 1) * 32;
            pa0 = *(const f32x4*)a2; pa1 = *(const f32x4*)(a2 + 4);
            pb0 = *(const f32x4*)b2; pb1 = *(const f32x4*)(b2 + 4);
        }
        bf16x8 af = sm[kb & 1][0][g * 64 + w * 16 + r];
        #pragma unroll
        for (int j = 0; j < 4; ++j) {
            bf16x8 bf = sm[kb & 1][1][g * 64 + j * 16 + r];
            acc[j] = mfma16(af, bf, acc[j]);
        }
    }

    #pragma unroll
    for (int j = 0; j < 4; ++j) {
        int col = cb + j * 16 + r;
        #pragma unroll
        for (int q = 0; q < 4; ++q) {
            int row = rb + w * 16 + g * 4 + q;
            float v = acc[j][q];
            if (cb < 512)       dt_e[(size_t)row * 512 + col] = v;
            else if (cb < 1024) dt_s[(size_t)row * 512 + (col - 512)] = v;
            else {
                int c0 = col - 1024;
                gh[(size_t)row * 3456 + c0] = v + b_hh[c0];
            }
        }
    }
}

// ---------------------------------------------------------------------------
// K2: attention logits, one 128x128 et-tile per block, fused tanh/vt epilogue,
// per-phase partial u. grid = 2048 linear, XCD-swizzled so the 4 col-phase
// blocks of one (e,b) enc tile share an XCD (enc fetched ~once from HBM).
// ---------------------------------------------------------------------------
__global__ __launch_bounds__(256) void k_attn(
    const float* __restrict__ enc_e, const float* __restrict__ enc_s,
    const float* __restrict__ W1e, const float* __restrict__ W1s,
    const float* __restrict__ vte, const float* __restrict__ vts,
    const float* __restrict__ dt_e, const float* __restrict__ dt_s,
    float* __restrict__ u_part)
{
    const int L = blockIdx.x;
    const int n = (L >> 3) & 3;                  // col phase 0..3
    const int G = (L & 7) + ((L >> 5) << 3);     // 0..511
    const int e = G >> 8;
    const int b = G & 255;

    const float* enc = e ? enc_s : enc_e;
    const float* W1  = e ? W1s  : W1e;
    const float* vt  = e ? vts  : vte;
    const float* dt  = e ? dt_s : dt_e;

    __shared__ bf16x8 sm[2][2][512];
    __shared__ float upart[2][128];

    const int t = threadIdx.x;
    const int w = t >> 6, wr = w >> 1, wc = w & 1;
    const int lane = t & 63, g = lane >> 4, r = lane & 15;
    const int s_row = t >> 1, s_h = t & 1;

    const int kg0 = 2 * s_h, kg1 = 2 * s_h + 1;
    const int swz0 = kg0 * 128 + ((s_row & 112) | ((s_row ^ (kg0 << 2)) & 15));
    const int swz1 = kg1 * 128 + ((s_row & 112) | ((s_row ^ (kg1 << 2)) & 15));

    int ai[4], bi[4];
    #pragma unroll
    for (int i = 0; i < 4; ++i) {
        ai[i] = g * 128 + wr * 64 + i * 16 + ((r ^ (g << 2)) & 15);
        bi[i] = g * 128 + wc * 64 + i * 16 + ((r ^ (g << 2)) & 15);
    }

    const float* Ap = enc + (size_t)(b * 128 + s_row) * 512 + s_h * 16;
    const float* Bp = W1 + (size_t)(n * 128 + s_row) * 512 + s_h * 16;

    f32x4 pa0 = ((const f32x4*)Ap)[0], pa1 = ((const f32x4*)Ap)[1],
          pa2 = ((const f32x4*)Ap)[2], pa3 = ((const f32x4*)Ap)[3];
    f32x4 pb0 = ((const f32x4*)Bp)[0], pb1 = ((const f32x4*)Bp)[1],
          pb2 = ((const f32x4*)Bp)[2], pb3 = ((const f32x4*)Bp)[3];

    f32x4 acc[4][4];
    #pragma unroll
    for (int i = 0; i < 4; ++i)
        #pragma unroll
        for (int j = 0; j < 4; ++j) acc[i][j] = (f32x4){0.f, 0.f, 0.f, 0.f};

    for (int kb = 0; kb < 16; ++kb) {
        const int buf = kb & 1;
        sm[buf][0][swz0] = pack8(pa0, pa1);
        sm[buf][0][swz1] = pack8(pa2, pa3);
        sm[buf][1][swz0] = pack8(pb0, pb1);
        sm[buf][1][swz1] = pack8(pb2, pb3);
        __syncthreads();
        if (kb + 1 < 16) {
            const float* a2 = Ap + (kb + 1) * 32;
            const float* b2 = Bp + (kb + 1) * 32;
            pa0 = ((const f32x4*)a2)[0]; pa1 = ((const f32x4*)a2)[1];
            pa2 = ((const f32x4*)a2)[2]; pa3 = ((const f32x4*)a2)[3];
            pb0 = ((const f32x4*)b2)[0]; pb1 = ((const f32x4*)b2)[1];
            pb2 = ((const f32x4*)b2)[2]; pb3 = ((const f32x4*)b2)[3];
        }
        bf16x8 af[4], bfr[4];
        #pragma unroll
        for (int i = 0; i < 4; ++i) af[i]  = sm[buf][0][ai[i]];
        #pragma unroll
        for (int j = 0; j < 4; ++j) bfr[j] = sm[buf][1][bi[j]];
        #pragma unroll
        for (int i = 0; i < 4; ++i)
            #pragma unroll
            for (int j = 0; j < 4; ++j)
                acc[i][j] = mfma16(af[i], bfr[j], acc[i][j]);
    }

    // fused epilogue: partial u_row = sum over this block's 128 cols
    float dv[4], vv[4];
    #pragma unroll
    for (int j = 0; j < 4; ++j) {
        int col = n * 128 + wc * 64 + j * 16 + r;
        dv[j] = dt[(size_t)b * 512 + col];
        vv[j] = vt[col];
    }
    #pragma unroll
    for (int i = 0; i < 4; ++i) {
        #pragma unroll
        for (int q = 0; q < 4; ++q) {
            float s = 0.f;
            #pragma unroll
            for (int j = 0; j < 4; ++j)
                s += vv[j] * tanh_fast(acc[i][j][q] + dv[j]);
            #pragma unroll
            for (int m = 1; m < 16; m <<= 1) s += __shfl_xor(s, m);
            if (r == 0) upart[wc][wr * 64 + i * 16 + g * 4 + q] = s;
        }
    }
    __syncthreads();
    if (t < 128)
        u_part[((size_t)(n * 2 + e)) * BN_ + b * 128 + t] = upart[0][t] + upart[1][t];
}

// ---------------------------------------------------------------------------
// K3: masked softmax (summing 4 u partials), plan softmax, ctx weighted sums
// (f32x4 loads), y_ctx via atomicAdd into zeroed buffer.
// grid = (256 batches, 2 row-halves), 256 threads.
// ---------------------------------------------------------------------------
__global__ __launch_bounds__(256) void k_ctx(
    const float* __restrict__ u_part, const int* __restrict__ mask_e,
    const int* __restrict__ mask_s, const float* __restrict__ enc_e,
    const float* __restrict__ enc_s, const float* __restrict__ prev_h,
    const float* __restrict__ plan_W, const float* __restrict__ plan_b,
    const float* __restrict__ prev_y,
    float* __restrict__ y_ctx, float* __restrict__ plan_out)
{
    const int b = blockIdx.x;
    const int rh = blockIdx.y;
    const int t = threadIdx.x;
    const int lane = t & 63, wid = t >> 6, half = t >> 7, n = t & 127;

    __shared__ float aw[2][128];
    __shared__ float red[16];
    __shared__ float planv[2];

    const int* mask = half ? mask_s : mask_e;
    float uv = u_part[(size_t)(0 * 2 + half) * BN_ + b * 128 + n]
             + u_part[(size_t)(1 * 2 + half) * BN_ + b * 128 + n]
             + u_part[(size_t)(2 * 2 + half) * BN_ + b * 128 + n]
             + u_part[(size_t)(3 * 2 + half) * BN_ + b * 128 + n];
    bool msk = mask[b * 128 + n] != 0;
    float val = msk ? -3.4e38f : uv;

    float mx = val;
    #pragma unroll
    for (int m = 1; m < 64; m <<= 1) mx = fmaxf(mx, __shfl_xor(mx, m));
    if (lane == 0) red[wid] = mx;
    __syncthreads();
    mx = fmaxf(red[half * 2], red[half * 2 + 1]);
    float ex = msk ? 0.f : __expf(uv - mx);
    float sm = ex;
    #pragma unroll
    for (int m = 1; m < 64; m <<= 1) sm += __shfl_xor(sm, m);
    if (lane == 0) red[4 + wid] = sm;
    __syncthreads();
    sm = red[4 + half * 2] + red[4 + half * 2 + 1];
    aw[half][n] = ex / sm;

    // plan logits (exact f32)
    float p0 = 0.f, p1 = 0.f;
    for (int i = t; i < DD; i += 256) {
        float hv = prev_h[(size_t)b * DD + i];
        p0 += hv * plan_W[i];
        p1 += hv * plan_W[DD + i];
    }
    #pragma unroll
    for (int m = 1; m < 64; m <<= 1) { p0 += __shfl_xor(p0, m); p1 += __shfl_xor(p1, m); }
    if (lane == 0) { red[8 + wid] = p0; red[12 + wid] = p1; }
    __syncthreads();
    if (t == 0) {
        float l0 = red[8] + red[9] + red[10] + red[11] + plan_b[0];
        float l1 = red[12] + red[13] + red[14] + red[15] + plan_b[1];
        float mm = fmaxf(l0, l1);
        float e0 = __expf(l0 - mm), e1 = __expf(l1 - mm);
        float ss = e0 + e1;
        planv[0] = e0 / ss; planv[1] = e1 / ss;
        if (rh == 0) {
            plan_out[b * 2 + 0] = planv[0];
            plan_out[b * 2 + 1] = planv[1];
        }
    }
    __syncthreads();

    // weighted sum over 64 rows (this row-half), f32x4 cols
    const int ee = t >> 7;           // encoder
    const int tt = t & 127;          // col group (4 cols)
    const float pl = planv[ee];
    const float* base = (ee ? enc_s : enc_e) + (size_t)b * 65536 + (size_t)(rh * 64) * 512 + tt * 4;
    f32x4 accv = {0.f, 0.f, 0.f, 0.f};
    #pragma unroll 4
    for (int row = 0; row < 64; ++row) {
        f32x4 v = *(const f32x4*)(base + (size_t)row * 512);
        float a = aw[ee][rh * 64 + row];
        accv += a * v;
    }
    float* dst = y_ctx + (size_t)b * 1024 + 512 + tt * 4;
    atomicAdd(dst + 0, pl * accv[0]);
    atomicAdd(dst + 1, pl * accv[1]);
    atomicAdd(dst + 2, pl * accv[2]);
    atomicAdd(dst + 3, pl * accv[3]);

    if (rh == 0 && t < 128) {
        f32x4 v = *(const f32x4*)(prev_y + (size_t)b * 512 + t * 4);
        *(f32x4*)(y_ctx + (size_t)b * 1024 + t * 4) = v;
    }
}

// ---------------------------------------------------------------------------
// K4a: 64x64-tile GEMM (small x = y_ctx@Wc^T)
// ---------------------------------------------------------------------------
__global__ __launch_bounds__(256) void k_gemm_bias(
    const float* __restrict__ A, const float* __restrict__ B,
    const float* __restrict__ bias, float* __restrict__ C,
    int K, int ldc)
{
    const int cb = blockIdx.x * 64;
    const int rb = blockIdx.y * 64;
    const int t  = threadIdx.x;
    const int w = t >> 6, lane = t & 63, g = lane >> 4, r = lane & 15;
    const int s_row = t >> 2, s_kc = t & 3;

    __shared__ bf16x8 sm[2][2][256];

    const float* Ap = A + (size_t)(rb + s_row) * K + s_kc * 8;
    const float* Bp = B + (size_t)(cb + s_row) * K + s_kc * 8;

    const int KS = K >> 5;
    f32x4 pa0 = *(const f32x4*)Ap, pa1 = *(const f32x4*)(Ap + 4);
    f32x4 pb0 = *(const f32x4*)Bp, pb1 = *(const f32x4*)(Bp + 4);

    f32x4 acc[4] = {{0,0,0,0},{0,0,0,0},{0,0,0,0},{0,0,0,0}};

    for (int kb = 0; kb < KS; ++kb) {
        sm[kb & 1][0][s_kc * 64 + s_row] = pack8(pa0, pa1);
        sm[kb & 1][1][s_kc * 64 + s_row] = pack8(pb0, pb1);
        __syncthreads();
        if (kb + 1 < KS) {
            const float* a2 = Ap + (kb + 1) * 32;
            const float* b2 = Bp + (kb + 1) * 32;
            pa0 = *(const f32x4*)a2; pa1 = *(const f32x4*)(a2 + 4);
            pb0 = *(const f32x4*)b2; pb1 = *(const f32x4*)(b2 + 4);
        }
        bf16x8 af = sm[kb & 1][0][g * 64 + w * 16 + r];
        #pragma unroll
        for (int j = 0; j < 4; ++j) {
            bf16x8 bf = sm[kb & 1][1][g * 64 + j * 16 + r];
            acc[j] = mfma16(af, bf, acc[j]);
        }
    }
    #pragma unroll
    for (int j = 0; j < 4; ++j) {
        int col = cb + j * 16 + r;
        float bv = bias ? bias[col] : 0.f;
        #pragma unroll
        for (int q = 0; q < 4; ++q) {
            int row = rb + w * 16 + g * 4 + q;
            C[(size_t)row * ldc + col] = acc[j][q] + bv;
        }
    }
}

// ---------------------------------------------------------------------------
// K5: GRU gates. grid=(3, BS), 384 thr.
// ---------------------------------------------------------------------------
__global__ __launch_bounds__(384) void k_gru(
    const float* __restrict__ gx, const float* __restrict__ gh,
    const float* __restrict__ prev_h, float* __restrict__ h_new,
    float* __restrict__ out_hidden)
{
    int d = blockIdx.x * 384 + threadIdx.x;   // 0..1151
    int b = blockIdx.y;
    size_t o3 = (size_t)b * 3456;
    float xr = gx[o3 + d], xz = gx[o3 + 1152 + d], xn = gx[o3 + 2304 + d];
    float hr = gh[o3 + d], hz = gh[o3 + 1152 + d], hn = gh[o3 + 2304 + d];
    float rr = 1.f / (1.f + __expf(-(xr + hr)));
    float zz = 1.f / (1.f + __expf(-(xz + hz)));
    float nv = tanhf(xn + rr * hn);
    float hv = (1.f - zz) * nv + zz * prev_h[(size_t)b * DD + d];
    h_new[(size_t)b * DD + d] = hv;
    out_hidden[(size_t)b * DD + d] = hv;
}

// ---------------------------------------------------------------------------
extern "C" void kernel_launch(void* const* d_in, const int* in_sizes, int n_in,
                              void* d_out, int out_size, void* d_ws, size_t ws_size,
                              hipStream_t stream)
{
    const float* prev_y = (const float*)d_in[0];
    const float* prev_h = (const float*)d_in[1];
    const float* enc_e  = (const float*)d_in[2];
    const float* enc_s  = (const float*)d_in[3];
    const int*   mask_e = (const int*)d_in[5];
    const int*   mask_s = (const int*)d_in[6];
    const float* W1e    = (const float*)d_in[7];
    const float* W2e    = (const float*)d_in[8];
    const float* vte    = (const float*)d_in[9];
    const float* W1s    = (const float*)d_in[10];
    const float* W2s    = (const float*)d_in[11];
    const float* vts    = (const float*)d_in[12];
    const float* plan_W = (const float*)d_in[13];
    const float* plan_b = (const float*)d_in[14];
    const float* Wc     = (const float*)d_in[15];
    const float* bc     = (const float*)d_in[16];
    const float* w_ih   = (const float*)d_in[17];
    const float* w_hh   = (const float*)d_in[18];
    const float* b_ih   = (const float*)d_in[19];
    const float* b_hh   = (const float*)d_in[20];
    const float* Wout   = (const float*)d_in[21];
    const float* bout   = (const float*)d_in[22];

    float* out = (float*)d_out;
    float* ws  = (float*)d_ws;

    // workspace layout (with lifetime-based aliasing):
    float* gh     = ws;                    // 884736   (K1 -> K5)
    float* big2   = ws + 884736;           // 884736:  dt_e|dt_s (K1->K2) then gx (K4b->K5)
    float* upxx   = big2 + 884736;         // 262144:  u_part (K2->K3) then xx (K4a->K4b)
    float* y_ctx  = upxx + 262144;         // 262144   (K3 -> K4a)
    float* h_new  = y_ctx + 262144;        // 294912   (K5 -> K6)

    float* dt_e  = big2;
    float* dt_s  = big2 + 131072;
    float* gx    = big2;
    float* u_part = upxx;
    float* xx    = upxx;

    float* dec_out  = out;                 // 256*32000
    float* dec_hid  = out + 8192000;       // 256*1152
    float* plan_out = out + 8486912;       // 256*2

    // zero y_ctx (ctx accumulated via atomics)
    hipMemsetAsync(y_ctx, 0, 262144 * sizeof(float), stream);

    // K1: dt_e, dt_s, gh
    k_prevh<<<dim3(70, 4), 256, 0, stream>>>(prev_h, W2e, W2s, w_hh, b_hh,
                                             dt_e, dt_s, gh);

    // K2: attention logit partials (2048 XCD-swizzled blocks)
    k_attn<<<dim3(2048), 256, 0, stream>>>(
        enc_e, enc_s, W1e, W1s, vte, vts, dt_e, dt_s, u_part);

    // K3: softmax + ctx + plan + y_ctx
    k_ctx<<<dim3(BS_, 2), 256, 0, stream>>>(u_part, mask_e, mask_s, enc_e, enc_s,
                                            prev_h, plan_W, plan_b, prev_y,
                                            y_ctx, plan_out);

    // K4a: x = y_ctx @ Wc^T + bc
    k_gemm_bias<<<dim3(8, 4), 256, 0, stream>>>(y_ctx, Wc, bc, xx, 1024, 512);
    // K4b: gx = x @ w_ih^T + b_ih
    k_tile128<<<dim3(2, 27), 256, 0, stream>>>(xx, w_ih, b_ih, gx, 512, 3456);

    // K5: GRU
    k_gru<<<dim3(3, BS_), 384, 0, stream>>>(gx, gh, prev_h, h_new, dec_hid);

    // K6: dec_output = h_new @ Wout^T + bout (XCD-swizzled Wout streaming)
    k_vocab<<<dim3(512), 256, 0, stream>>>(h_new, Wout, bout, dec_out,
                                           1152, 32000);
}